// Round 1
// baseline (1286.801 us; speedup 1.0000x reference)
//
#include <hip/hip_runtime.h>

// ---------------------------------------------------------------------------
// WordEncoder: 6-layer local-attention transformer encoder on MI355X (gfx950)
//
// Structure per call:
//   tcast x6 (weights f32 -> bf16, transposed to [N][K])
//   embed -> x (f32)
//   scan word_start -> tgt
//   6x { LN1 -> QKV gemm -> attn -> WO gemm(+res) -> LN2 -> FFN1 gemm(gelu)
//        -> FFN2 gemm(+bias+res) }
//   final-LN fused into gather -> d_out (zeroed first)
//
// GEMMs: bf16 MFMA 16x16x32, 128x128 tile, 4 waves (2x2), BK=32,
// global_load_lds dwordx4 staging (linear LDS, m97-style 2-barrier loop).
// Workspace: ~137 MiB (qkv and ffn-hidden share one region; disjoint in time).
// ---------------------------------------------------------------------------

#define S_LEN 8192
#define BATCH 4
#define DMODEL 256
#define NHEAD 8
#define WIN 64
#define NWIN 128
#define NLAYER 6
#define FFDIM 1024
#define MROWS (BATCH * S_LEN)

typedef float __attribute__((ext_vector_type(4))) f32x4;
typedef unsigned short u16;
typedef unsigned short __attribute__((ext_vector_type(4))) u16x4;

__device__ __forceinline__ u16 f2bf(float f) {
  unsigned u = __builtin_bit_cast(unsigned, f);
  u += 0x7fffu + ((u >> 16) & 1u);   // round-to-nearest-even
  return (u16)(u >> 16);
}
__device__ __forceinline__ float bf2f(u16 h) {
  unsigned u = ((unsigned)h) << 16;
  return __builtin_bit_cast(float, u);
}

// D = A(16x32 bf16) * B(32x16 bf16) + D, f32 acc. Operands held as 128-bit
// containers; inline asm avoids builtin signature differences across ROCm.
__device__ __forceinline__ void mfma16(f32x4& d, f32x4 a, f32x4 b) {
  asm volatile("v_mfma_f32_16x16x32_bf16 %0, %1, %2, %0"
               : "+v"(d) : "v"(a), "v"(b));
}
// MFMA(asm) -> VALU-read hazard guard (hazard recognizer can't see into asm)
#define MFMA_FENCE() asm volatile("s_nop 7\n\ts_nop 7")

__device__ __forceinline__ void gload_lds16(const void* g, void* l) {
  __builtin_amdgcn_global_load_lds(
      (__attribute__((address_space(1))) void*)g,
      (__attribute__((address_space(3))) void*)l, 16, 0, 0);
}

// ---------------------------------------------------------------- embed ----
__global__ __launch_bounds__(64) void embed_kernel(
    const int* __restrict__ ids, const float* __restrict__ emb,
    const float* __restrict__ pos, float* __restrict__ x) {
  int r = blockIdx.x;                 // 0..MROWS-1
  int s = r & (S_LEN - 1);
  int lane = threadIdx.x;
  int id = ids[r];
  f32x4 e = *(const f32x4*)(emb + id * DMODEL + lane * 4);
  f32x4 p = *(const f32x4*)(pos + s * DMODEL + lane * 4);
  *(f32x4*)(x + r * DMODEL + lane * 4) = e + p;
}

// ----------------------------------------------------------------- zero ----
__global__ void zero_kernel(float* __restrict__ p, int n4) {
  int i = blockIdx.x * blockDim.x + threadIdx.x;
  int stride = gridDim.x * blockDim.x;
  f32x4 z = {0.f, 0.f, 0.f, 0.f};
  for (; i < n4; i += stride) ((f32x4*)p)[i] = z;
}

// ------------------------------------------------- weight transpose+cast ---
// src: [L][K][N] f32.  dst: layer l, dst[l*dls + (rowOff+n)*K + k] = bf16(src)
__global__ void tcast_kernel(const float* __restrict__ src, u16* __restrict__ dst,
                             int total, int K, int N, int dls, int rowOff) {
  int i = blockIdx.x * blockDim.x + threadIdx.x;
  int stride = gridDim.x * blockDim.x;
  int KN = K * N;
  for (; i < total; i += stride) {
    int l = i / KN;
    int rem = i - l * KN;
    int k = rem / N;
    int n = rem - k * N;
    dst[l * dls + (rowOff + n) * K + k] = f2bf(src[i]);
  }
}

// ------------------------------------------------------------------- LN ----
// one wave per row (64 lanes x float4), bf16 output
__global__ __launch_bounds__(256) void ln_kernel(
    const float* __restrict__ x, const float* __restrict__ g,
    const float* __restrict__ b, u16* __restrict__ y) {
  int wid = threadIdx.x >> 6, lane = threadIdx.x & 63;
  int r = blockIdx.x * 4 + wid;
  f32x4 v = *(const f32x4*)(x + r * DMODEL + lane * 4);
  float s = v[0] + v[1] + v[2] + v[3];
  float q = v[0] * v[0] + v[1] * v[1] + v[2] * v[2] + v[3] * v[3];
  for (int off = 32; off; off >>= 1) {
    s += __shfl_xor(s, off, 64);
    q += __shfl_xor(q, off, 64);
  }
  float mean = s * (1.0f / DMODEL);
  float var = q * (1.0f / DMODEL) - mean * mean;
  float rs = rsqrtf(var + 1e-5f);
  f32x4 gg = *(const f32x4*)(g + lane * 4);
  f32x4 bb = *(const f32x4*)(b + lane * 4);
  u16x4 o;
  for (int j = 0; j < 4; ++j) o[j] = f2bf((v[j] - mean) * rs * gg[j] + bb[j]);
  *(u16x4*)(y + r * DMODEL + lane * 4) = o;
}

// ----------------------------------------------------------------- GEMM ----
// C[M][N] = A[M][K] @ Bt[N][K]^T  (+bias[N]) (gelu) (+res[M][N])
// 128x128 tile, 256 thr = 4 waves (2x2), each wave 64x64 via 4x4 16x16 frags.
template <bool OUT_BF16, bool GELU_ACT, bool HAS_BIAS, bool HAS_RES>
__global__ __launch_bounds__(256) void gemm_kernel(
    const u16* __restrict__ A, const u16* __restrict__ Bt,
    void* __restrict__ Cout, const float* __restrict__ bias,
    const float* __restrict__ res, int M, int N, int K) {
  __shared__ u16 As[128 * 32];
  __shared__ u16 Bs[128 * 32];
  int tid = threadIdx.x;
  int lane = tid & 63, wid = tid >> 6;
  int l15 = lane & 15, l4 = lane >> 4;
  int wm = wid >> 1, wn = wid & 1;
  int bm = blockIdx.y * 128, bn = blockIdx.x * 128;

  const u16* Ab = A + bm * K;
  const u16* Bb = Bt + bn * K;

  f32x4 acc[4][4] = {};

  int row0 = tid >> 2;                  // chunk c=0: rows 0..63
  int kc0 = (tid & 3) * 8;              // 8-elem (16B) sub-chunk
  char* AsDst = (char*)As + wid * 1024; // wave-uniform LDS bases
  char* BsDst = (char*)Bs + wid * 1024;

  for (int kt = 0; kt < K; kt += 32) {
    gload_lds16(Ab + row0 * K + kt + kc0, AsDst);
    gload_lds16(Ab + (row0 + 64) * K + kt + kc0, AsDst + 4096);
    gload_lds16(Bb + row0 * K + kt + kc0, BsDst);
    gload_lds16(Bb + (row0 + 64) * K + kt + kc0, BsDst + 4096);
    __syncthreads();
    f32x4 af[4], bf[4];
#pragma unroll
    for (int m = 0; m < 4; ++m)
      af[m] = *(const f32x4*)(As + (wm * 64 + m * 16 + l15) * 32 + l4 * 8);
#pragma unroll
    for (int n = 0; n < 4; ++n)
      bf[n] = *(const f32x4*)(Bs + (wn * 64 + n * 16 + l15) * 32 + l4 * 8);
#pragma unroll
    for (int m = 0; m < 4; ++m)
#pragma unroll
      for (int n = 0; n < 4; ++n) mfma16(acc[m][n], af[m], bf[n]);
    __syncthreads();
  }
  MFMA_FENCE();

  int colBase = bn + wn * 64 + l15;
#pragma unroll
  for (int n = 0; n < 4; ++n) {
    int col = colBase + n * 16;
    float bv = 0.0f;
    if (HAS_BIAS) bv = bias[col];
#pragma unroll
    for (int m = 0; m < 4; ++m) {
      int rowB = bm + wm * 64 + m * 16 + l4 * 4;
#pragma unroll
      for (int j = 0; j < 4; ++j) {
        float v = acc[m][n][j] + bv;
        if (GELU_ACT) {
          float t = v;
          v = 0.5f * t * (1.0f + tanhf(0.7978845608028654f *
                                       (t + 0.044715f * t * t * t)));
        }
        long off = (long)(rowB + j) * N + col;
        if (HAS_RES) v += res[off];
        if (OUT_BF16)
          ((u16*)Cout)[off] = f2bf(v);
        else
          ((float*)Cout)[off] = v;
      }
    }
  }
}

// ------------------------------------------------------------ attention ----
// one block per (window, head, batch): Q(64x32) x Kctx(192x32)^T -> softmax
// -> P(64x192) x Vctx(192x32).  4 waves, wave w owns q-rows w*16..w*16+15.
__global__ __launch_bounds__(256) void attn_kernel(
    const u16* __restrict__ qkv,   // [MROWS][768]: q|k|v per row
    const int* __restrict__ amask, // [BATCH][S_LEN]
    u16* __restrict__ ao) {        // [MROWS][256]
  int win = blockIdx.x, h = blockIdx.y, b = blockIdx.z;
  int tid = threadIdx.x, lane = tid & 63, wid = tid >> 6;
  int l15 = lane & 15, l4 = lane >> 4;

  __shared__ u16 Ks[192 * 32];   // [key][dh]
  __shared__ u16 Vts[32 * 200];  // [dh][key], padded stride 200
  __shared__ u16 Ps[64 * 200];   // [qrow][key], padded stride 200
  __shared__ unsigned char valid[192];

  int t0 = win * WIN - WIN;  // token index of context key 0

  if (tid < 192) {
    int t = t0 + tid;
    valid[tid] = (t >= 0 && t < S_LEN && amask[b * S_LEN + t] != 0) ? 1 : 0;
  }
  // K staging: 768 16B-chunks via global_load_lds (clamped rows; masked later)
#pragma unroll
  for (int c = 0; c < 3; ++c) {
    int chunk = c * 256 + tid;
    int key = chunk >> 2, kc = chunk & 3;
    int t = t0 + key;
    t = t < 0 ? 0 : (t >= S_LEN ? S_LEN - 1 : t);
    const u16* g = qkv + (b * S_LEN + t) * 768 + 256 + h * 32 + kc * 8;
    gload_lds16(g, (char*)Ks + c * 4096 + wid * 1024);
  }
  // V staged transposed (scalar; coalesced global reads)
  for (int e = tid; e < 192 * 32; e += 256) {
    int key = e >> 5, d = e & 31;
    int t = t0 + key;
    t = t < 0 ? 0 : (t >= S_LEN ? S_LEN - 1 : t);
    Vts[d * 200 + key] = qkv[(b * S_LEN + t) * 768 + 512 + h * 32 + d];
  }
  __syncthreads();

  int qrow = b * S_LEN + win * WIN + wid * 16 + l15;
  f32x4 aq = *(const f32x4*)(qkv + qrow * 768 + h * 32 + l4 * 8);

  f32x4 sacc[12] = {};
#pragma unroll
  for (int f = 0; f < 12; ++f) {
    f32x4 bk = *(const f32x4*)(Ks + (f * 16 + l15) * 32 + l4 * 8);
    mfma16(sacc[f], aq, bk);
  }
  MFMA_FENCE();

  const float scale = 0.17677669529663687f;  // 1/sqrt(32)
  float mrow[4] = {-1e30f, -1e30f, -1e30f, -1e30f};
#pragma unroll
  for (int f = 0; f < 12; ++f) {
    bool ok = valid[f * 16 + l15] != 0;
#pragma unroll
    for (int j = 0; j < 4; ++j) {
      float sv = ok ? sacc[f][j] * scale : -1e9f;
      sacc[f][j] = sv;
      mrow[j] = fmaxf(mrow[j], sv);
    }
  }
#pragma unroll
  for (int j = 0; j < 4; ++j)
#pragma unroll
    for (int off = 1; off < 16; off <<= 1)
      mrow[j] = fmaxf(mrow[j], __shfl_xor(mrow[j], off, 64));

  float ssum[4] = {0.f, 0.f, 0.f, 0.f};
#pragma unroll
  for (int f = 0; f < 12; ++f)
#pragma unroll
    for (int j = 0; j < 4; ++j) {
      float p = __expf(sacc[f][j] - mrow[j]);
      sacc[f][j] = p;
      ssum[j] += p;
    }
#pragma unroll
  for (int j = 0; j < 4; ++j)
#pragma unroll
    for (int off = 1; off < 16; off <<= 1)
      ssum[j] += __shfl_xor(ssum[j], off, 64);

  // P -> LDS (each wave writes only its own 16 rows)
#pragma unroll
  for (int f = 0; f < 12; ++f)
#pragma unroll
    for (int j = 0; j < 4; ++j)
      Ps[(wid * 16 + l4 * 4 + j) * 200 + f * 16 + l15] = f2bf(sacc[f][j]);
  __syncthreads();

  f32x4 oacc[2] = {};
#pragma unroll
  for (int kk = 0; kk < 6; ++kk) {
    f32x4 ap = *(const f32x4*)(Ps + (wid * 16 + l15) * 200 + kk * 32 + l4 * 8);
#pragma unroll
    for (int nf = 0; nf < 2; ++nf) {
      f32x4 bv = *(const f32x4*)(Vts + (nf * 16 + l15) * 200 + kk * 32 + l4 * 8);
      mfma16(oacc[nf], ap, bv);
    }
  }
  MFMA_FENCE();

  float inv[4];
#pragma unroll
  for (int j = 0; j < 4; ++j) inv[j] = 1.0f / ssum[j];
#pragma unroll
  for (int nf = 0; nf < 2; ++nf)
#pragma unroll
    for (int j = 0; j < 4; ++j) {
      int orow = b * S_LEN + win * WIN + wid * 16 + l4 * 4 + j;
      ao[orow * 256 + h * 32 + nf * 16 + l15] = f2bf(oacc[nf][j] * inv[j]);
    }
}

// ------------------------------------------------------------- scan --------
// per-batch inclusive scan of word_start -> tgt row index (or -1)
__global__ __launch_bounds__(256) void scan_kernel(const int* __restrict__ wsrt,
                                                   int* __restrict__ tgt) {
  __shared__ int part[256];
  int b = blockIdx.x, tid = threadIdx.x;
  const int* src = wsrt + b * S_LEN;
  int* dst = tgt + b * S_LEN;
  int base = tid * 32;
  int loc[32];
  int s = 0;
#pragma unroll
  for (int i = 0; i < 32; ++i) {
    loc[i] = src[base + i];
    s += loc[i];
  }
  part[tid] = s;
  __syncthreads();
  for (int off = 1; off < 256; off <<= 1) {
    int v = (tid >= off) ? part[tid - off] : 0;
    __syncthreads();
    part[tid] += v;
    __syncthreads();
  }
  int cum = part[tid] - s;  // exclusive prefix
#pragma unroll
  for (int i = 0; i < 32; ++i) {
    cum += loc[i];
    dst[base + i] = (loc[i] > 0) ? (cum - 1) : -1;
  }
}

// ------------------------------------------------- final LN + gather -------
__global__ __launch_bounds__(64) void gather_ln_kernel(
    const float* __restrict__ x, const int* __restrict__ tgt,
    const float* __restrict__ g, const float* __restrict__ b,
    float* __restrict__ out) {
  int r = blockIdx.x;
  int tg = tgt[r];
  if (tg < 0) return;
  int bIdx = r >> 13;  // / S_LEN
  int lane = threadIdx.x;
  f32x4 v = *(const f32x4*)(x + r * DMODEL + lane * 4);
  float s = v[0] + v[1] + v[2] + v[3];
  float q = v[0] * v[0] + v[1] * v[1] + v[2] * v[2] + v[3] * v[3];
  for (int off = 32; off; off >>= 1) {
    s += __shfl_xor(s, off, 64);
    q += __shfl_xor(q, off, 64);
  }
  float mean = s * (1.0f / DMODEL);
  float var = q * (1.0f / DMODEL) - mean * mean;
  float rs = rsqrtf(var + 1e-5f);
  f32x4 gg = *(const f32x4*)(g + lane * 4);
  f32x4 bb = *(const f32x4*)(b + lane * 4);
  f32x4 o;
  for (int j = 0; j < 4; ++j) o[j] = (v[j] - mean) * rs * gg[j] + bb[j];
  *(f32x4*)(out + (bIdx * S_LEN + tg) * DMODEL + lane * 4) = o;
}

// ---------------------------------------------------------------------------
extern "C" void kernel_launch(void* const* d_in, const int* in_sizes, int n_in,
                              void* d_out, int out_size, void* d_ws,
                              size_t ws_size, hipStream_t stream) {
  const int* ids = (const int*)d_in[0];
  const int* amask = (const int*)d_in[1];
  const int* wstart = (const int*)d_in[2];
  const float* emb = (const float*)d_in[3];
  const float* pos = (const float*)d_in[4];
  const float* ln1g = (const float*)d_in[5];
  const float* ln1b = (const float*)d_in[6];
  const float* wq = (const float*)d_in[7];
  const float* wk = (const float*)d_in[8];
  const float* wv = (const float*)d_in[9];
  const float* wo = (const float*)d_in[10];
  const float* ln2g = (const float*)d_in[11];
  const float* ln2b = (const float*)d_in[12];
  const float* w1 = (const float*)d_in[13];
  const float* b1 = (const float*)d_in[14];
  const float* w2 = (const float*)d_in[15];
  const float* b2 = (const float*)d_in[16];
  const float* lnfg = (const float*)d_in[17];
  const float* lnfb = (const float*)d_in[18];

  // workspace layout (bytes)
  char* ws = (char*)d_ws;
  const size_t OFF_X = 0;                  // f32 [32768][256]   33.55 MB
  const size_t OFF_XB = 33554432;          // bf16 [32768][256]  16.78 MB
  const size_t OFF_AO = 50331648;          // bf16 [32768][256]  16.78 MB
  const size_t OFF_BIG = 67108864;         // bf16, 67.11 MB (qkv / ffn-hidden)
  const size_t OFF_WQKVT = 134217728;      // 2.36 MB
  const size_t OFF_WOT = 136577024;        // 0.79 MB
  const size_t OFF_W1T = 137363456;        // 3.15 MB
  const size_t OFF_W2T = 140509184;        // 3.15 MB
  const size_t OFF_TGT = 143654912;        // 0.13 MB
  const size_t NEEDED = 143785984;
  if (ws_size < NEEDED) return;  // insufficient scratch; fail loudly (wrong out)

  float* x = (float*)(ws + OFF_X);
  u16* xb = (u16*)(ws + OFF_XB);
  u16* ao = (u16*)(ws + OFF_AO);
  u16* big = (u16*)(ws + OFF_BIG);  // qkv [32768][768] OR ffh [32768][1024]
  u16* WqkvT = (u16*)(ws + OFF_WQKVT);
  u16* WoT = (u16*)(ws + OFF_WOT);
  u16* W1T = (u16*)(ws + OFF_W1T);
  u16* W2T = (u16*)(ws + OFF_W2T);
  int* tgt = (int*)(ws + OFF_TGT);

  // weights -> bf16 transposed
  tcast_kernel<<<1024, 256, 0, stream>>>(wq, WqkvT, NLAYER * 256 * 256, 256, 256, 768 * 256, 0);
  tcast_kernel<<<1024, 256, 0, stream>>>(wk, WqkvT, NLAYER * 256 * 256, 256, 256, 768 * 256, 256);
  tcast_kernel<<<1024, 256, 0, stream>>>(wv, WqkvT, NLAYER * 256 * 256, 256, 256, 768 * 256, 512);
  tcast_kernel<<<1024, 256, 0, stream>>>(wo, WoT, NLAYER * 256 * 256, 256, 256, 256 * 256, 0);
  tcast_kernel<<<2048, 256, 0, stream>>>(w1, W1T, NLAYER * 256 * 1024, 256, 1024, 1024 * 256, 0);
  tcast_kernel<<<2048, 256, 0, stream>>>(w2, W2T, NLAYER * 1024 * 256, 1024, 256, 256 * 1024, 0);

  embed_kernel<<<MROWS, 64, 0, stream>>>(ids, emb, pos, x);
  zero_kernel<<<2048, 256, 0, stream>>>((float*)d_out, out_size / 4);
  scan_kernel<<<BATCH, 256, 0, stream>>>(wstart, tgt);

  for (int l = 0; l < NLAYER; ++l) {
    // x -> LN1 -> xb
    ln_kernel<<<MROWS / 4, 256, 0, stream>>>(x, ln1g + l * DMODEL, ln1b + l * DMODEL, xb);
    // qkv = xb @ WqkvT[l]
    gemm_kernel<true, false, false, false><<<dim3(6, 256), 256, 0, stream>>>(
        xb, WqkvT + l * 768 * 256, big, nullptr, nullptr, MROWS, 768, 256);
    // attention
    attn_kernel<<<dim3(NWIN, NHEAD, BATCH), 256, 0, stream>>>(big, amask, ao);
    // x += ao @ WoT[l]
    gemm_kernel<false, false, false, true><<<dim3(2, 256), 256, 0, stream>>>(
        ao, WoT + l * 256 * 256, x, nullptr, x, MROWS, 256, 256);
    // x -> LN2 -> xb
    ln_kernel<<<MROWS / 4, 256, 0, stream>>>(x, ln2g + l * DMODEL, ln2b + l * DMODEL, xb);
    // ffh = gelu(xb @ W1T[l] + b1)
    gemm_kernel<true, true, true, false><<<dim3(8, 256), 256, 0, stream>>>(
        xb, W1T + l * 1024 * 256, big, b1 + l * FFDIM, nullptr, MROWS, 1024, 256);
    // x += ffh @ W2T[l] + b2
    gemm_kernel<false, false, true, true><<<dim3(2, 256), 256, 0, stream>>>(
        big, W2T + l * 256 * 1024, x, b2 + l * DMODEL, x, MROWS, 256, 1024);
  }

  gather_ln_kernel<<<MROWS, 64, 0, stream>>>(x, tgt, lnfg, lnfb, (float*)d_out);
}

// Round 2
// 1056.554 us; speedup vs baseline: 1.2179x; 1.2179x over previous
//
#include <hip/hip_runtime.h>

// ---------------------------------------------------------------------------
// WordEncoder round 2: fused-LN GEMM epilogues, swizzled LDS, XCD swizzle,
// BK=64, vectorized full-line stores.
// ---------------------------------------------------------------------------

#define S_LEN 8192
#define BATCH 4
#define DMODEL 256
#define NHEAD 8
#define WIN 64
#define NWIN 128
#define NLAYER 6
#define FFDIM 1024
#define MROWS (BATCH * S_LEN)

typedef float __attribute__((ext_vector_type(4))) f32x4;
typedef unsigned short u16;
typedef unsigned short __attribute__((ext_vector_type(4))) u16x4;

__device__ __forceinline__ u16 f2bf(float f) {
  unsigned u = __builtin_bit_cast(unsigned, f);
  u += 0x7fffu + ((u >> 16) & 1u);
  return (u16)(u >> 16);
}

__device__ __forceinline__ void mfma16(f32x4& d, f32x4 a, f32x4 b) {
  asm volatile("v_mfma_f32_16x16x32_bf16 %0, %1, %2, %0"
               : "+v"(d) : "v"(a), "v"(b));
}
#define MFMA_FENCE() asm volatile("s_nop 7\n\ts_nop 7")

__device__ __forceinline__ void gload_lds16(const void* g, void* l) {
  __builtin_amdgcn_global_load_lds(
      (__attribute__((address_space(1))) void*)g,
      (__attribute__((address_space(3))) void*)l, 16, 0, 0);
}

__device__ __forceinline__ float gelu_f(float t) {
  float u = 0.7978845608028654f * (t + 0.044715f * t * t * t);
  float e = __expf(2.0f * u);
  float th = 1.0f - 2.0f / (e + 1.0f);
  return 0.5f * t * (1.0f + th);
}

// -------------------------------------------------- embed + LN1(layer 0) ---
__global__ __launch_bounds__(256) void embed_ln_kernel(
    const int* __restrict__ ids, const float* __restrict__ emb,
    const float* __restrict__ pos, const float* __restrict__ g,
    const float* __restrict__ b, float* __restrict__ x, u16* __restrict__ xb) {
  int wid = threadIdx.x >> 6, lane = threadIdx.x & 63;
  int r = blockIdx.x * 4 + wid;
  int s = r & (S_LEN - 1);
  int id = ids[r];
  f32x4 e = *(const f32x4*)(emb + (size_t)id * DMODEL + lane * 4);
  f32x4 p = *(const f32x4*)(pos + (size_t)s * DMODEL + lane * 4);
  f32x4 v = e + p;
  *(f32x4*)(x + (size_t)r * DMODEL + lane * 4) = v;
  float sm = v[0] + v[1] + v[2] + v[3];
  float q = v[0] * v[0] + v[1] * v[1] + v[2] * v[2] + v[3] * v[3];
  for (int off = 32; off; off >>= 1) {
    sm += __shfl_xor(sm, off, 64);
    q += __shfl_xor(q, off, 64);
  }
  float mean = sm * (1.0f / DMODEL);
  float var = q * (1.0f / DMODEL) - mean * mean;
  float rs = rsqrtf(var + 1e-5f);
  f32x4 gg = *(const f32x4*)(g + lane * 4);
  f32x4 bb = *(const f32x4*)(b + lane * 4);
  u16x4 o;
  for (int j = 0; j < 4; ++j) o[j] = f2bf((v[j] - mean) * rs * gg[j] + bb[j]);
  *(u16x4*)(xb + (size_t)r * DMODEL + lane * 4) = o;
}

// ----------------------------------------------------------------- zero ----
__global__ void zero_kernel(float* __restrict__ p, int n4) {
  int i = blockIdx.x * blockDim.x + threadIdx.x;
  int stride = gridDim.x * blockDim.x;
  f32x4 z = {0.f, 0.f, 0.f, 0.f};
  for (; i < n4; i += stride) ((f32x4*)p)[i] = z;
}

// ------------------------------------------------- weight transpose+cast ---
__global__ void tcast_kernel(const float* __restrict__ src, u16* __restrict__ dst,
                             int total, int K, int N, int dls, int rowOff) {
  int i = blockIdx.x * blockDim.x + threadIdx.x;
  int stride = gridDim.x * blockDim.x;
  int KN = K * N;
  for (; i < total; i += stride) {
    int l = i / KN;
    int rem = i - l * KN;
    int k = rem / N;
    int n = rem - k * N;
    dst[l * dls + (rowOff + n) * K + k] = f2bf(src[i]);
  }
}

// ------------------------------------------------------ plain GEMM (bf16) --
// C[M][N] = A[M][K] @ Bt[N][K]^T (+bias)(gelu), bf16 out via LDS-staged
// dwordx4 stores. 128x128 tile, 4 waves (2x2), BK=64, swizzled LDS.
// 1D grid with XCD-bijective swizzle, column-fastest within XCD.
template <bool GELU_ACT, bool HAS_BIAS>
__global__ __launch_bounds__(256, 4) void gemm_bf16(
    const u16* __restrict__ A, const u16* __restrict__ Bt,
    u16* __restrict__ C, const float* __restrict__ bias,
    int N, int K, int nx) {
  __shared__ u16 smem[16384];  // As 8192 | Bs 8192 ; epilogue reuses all
  u16* As = smem;
  u16* Bs = smem + 8192;

  int nwg = gridDim.x;
  int bid = blockIdx.x;
  int w = (bid & 7) * (nwg >> 3) + (bid >> 3);
  int cx = w % nx, ry = w / nx;
  int bm = ry * 128, bn = cx * 128;

  int tid = threadIdx.x, lane = tid & 63, wid = tid >> 6;
  int l15 = lane & 15, l4 = lane >> 4;
  int wm = wid >> 1, wn = wid & 1;

  const u16* Ab = A + (size_t)bm * K;
  const u16* Bb = Bt + (size_t)bn * K;

  f32x4 acc[4][4] = {};

  for (int kt = 0; kt < K; kt += 64) {
#pragma unroll
    for (int i = 0; i < 4; ++i) {
      int s = tid + i * 256;
      int r = s >> 3, c = (s & 7) ^ (r & 7);
      gload_lds16(Ab + (size_t)r * K + kt + c * 8,
                  (char*)As + (wid * 64 + i * 256) * 16);
    }
#pragma unroll
    for (int i = 0; i < 4; ++i) {
      int s = tid + i * 256;
      int r = s >> 3, c = (s & 7) ^ (r & 7);
      gload_lds16(Bb + (size_t)r * K + kt + c * 8,
                  (char*)Bs + (wid * 64 + i * 256) * 16);
    }
    __syncthreads();
#pragma unroll
    for (int t = 0; t < 2; ++t) {
      f32x4 af[4], bf[4];
#pragma unroll
      for (int m = 0; m < 4; ++m) {
        int r = wm * 64 + m * 16 + l15;
        af[m] = ((const f32x4*)As)[r * 8 + ((t * 4 + l4) ^ (r & 7))];
      }
#pragma unroll
      for (int n = 0; n < 4; ++n) {
        int r = wn * 64 + n * 16 + l15;
        bf[n] = ((const f32x4*)Bs)[r * 8 + ((t * 4 + l4) ^ (r & 7))];
      }
#pragma unroll
      for (int m = 0; m < 4; ++m)
#pragma unroll
        for (int n = 0; n < 4; ++n) mfma16(acc[m][n], af[m], bf[n]);
    }
    __syncthreads();
  }
  MFMA_FENCE();

  // epilogue: stage bf16 tile in LDS, then full-line dwordx4 stores
  u16* OutS = smem;
#pragma unroll
  for (int n = 0; n < 4; ++n) {
    int cl = wn * 64 + n * 16 + l15;
    float bv = HAS_BIAS ? bias[bn + cl] : 0.0f;
#pragma unroll
    for (int m = 0; m < 4; ++m)
#pragma unroll
      for (int j = 0; j < 4; ++j) {
        int rl = wm * 64 + m * 16 + l4 * 4 + j;
        float v = acc[m][n][j] + bv;
        if (GELU_ACT) v = gelu_f(v);
        OutS[rl * 128 + cl] = f2bf(v);
      }
  }
  __syncthreads();
#pragma unroll
  for (int i = 0; i < 8; ++i) {
    int q = tid + i * 256;  // 2048 16B chunks
    int r = q >> 4, cc = q & 15;
    *(f32x4*)(C + (size_t)(bm + r) * N + bn + cc * 8) = ((const f32x4*)OutS)[q];
  }
}

// ------------------------------------- GEMM + residual (+bias) + LN fused --
// x_new = x + A@Bt^T (+bias); xb = LN(x_new)*g+b  (if DO_LN)
// BM=128, BN=256 (= full N), 8 waves (2x4), BK=64, swizzled LDS.
template <bool DO_LN>
__global__ __launch_bounds__(512, 4) void gemm_res_ln(
    const u16* __restrict__ A, const u16* __restrict__ Bt,
    float* __restrict__ x, u16* __restrict__ xb,
    const float* __restrict__ bias, const float* __restrict__ g,
    const float* __restrict__ b, int K) {
  __shared__ u16 As[128 * 64];
  __shared__ u16 Bs[256 * 64];
  __shared__ float redS[128][4];
  __shared__ float redQ[128][4];

  int bm = blockIdx.x * 128;
  int tid = threadIdx.x, lane = tid & 63, wid = tid >> 6;
  int l15 = lane & 15, l4 = lane >> 4;
  int wm = wid >> 2, wn = wid & 3;

  const u16* Ab = A + (size_t)bm * K;
  f32x4 acc[4][4] = {};

  for (int kt = 0; kt < K; kt += 64) {
#pragma unroll
    for (int i = 0; i < 2; ++i) {
      int s = tid + i * 512;
      int r = s >> 3, c = (s & 7) ^ (r & 7);
      gload_lds16(Ab + (size_t)r * K + kt + c * 8,
                  (char*)As + (wid * 64 + i * 512) * 16);
    }
#pragma unroll
    for (int i = 0; i < 4; ++i) {
      int s = tid + i * 512;
      int r = s >> 3, c = (s & 7) ^ (r & 7);
      gload_lds16(Bt + (size_t)r * K + kt + c * 8,
                  (char*)Bs + (wid * 64 + i * 512) * 16);
    }
    __syncthreads();
#pragma unroll
    for (int t = 0; t < 2; ++t) {
      f32x4 af[4], bf[4];
#pragma unroll
      for (int m = 0; m < 4; ++m) {
        int r = wm * 64 + m * 16 + l15;
        af[m] = ((const f32x4*)As)[r * 8 + ((t * 4 + l4) ^ (r & 7))];
      }
#pragma unroll
      for (int n = 0; n < 4; ++n) {
        int r = wn * 64 + n * 16 + l15;
        bf[n] = ((const f32x4*)Bs)[r * 8 + ((t * 4 + l4) ^ (r & 7))];
      }
#pragma unroll
      for (int m = 0; m < 4; ++m)
#pragma unroll
        for (int n = 0; n < 4; ++n) mfma16(acc[m][n], af[m], bf[n]);
    }
    __syncthreads();
  }
  MFMA_FENCE();

  // pass 1: add bias + residual, accumulate row sums, stash partials
  float bv[4];
#pragma unroll
  for (int n = 0; n < 4; ++n)
    bv[n] = bias ? bias[wn * 64 + n * 16 + l15] : 0.0f;

#pragma unroll
  for (int m = 0; m < 4; ++m)
#pragma unroll
    for (int j = 0; j < 4; ++j) {
      int r = wm * 64 + m * 16 + l4 * 4 + j;
      size_t rowoff = (size_t)(bm + r) * DMODEL + wn * 64 + l15;
      float s = 0.f, q = 0.f;
#pragma unroll
      for (int n = 0; n < 4; ++n) {
        float v = acc[m][n][j] + bv[n] + x[rowoff + n * 16];
        acc[m][n][j] = v;
        s += v;
        q += v * v;
      }
      if (DO_LN) {
#pragma unroll
        for (int off = 1; off < 16; off <<= 1) {
          s += __shfl_xor(s, off, 64);
          q += __shfl_xor(q, off, 64);
        }
        if (l15 == 0) {
          redS[r][wn] = s;
          redQ[r][wn] = q;
        }
      }
    }
  if (DO_LN) __syncthreads();

  // pass 2: finish LN, write x (f32) and xb (bf16)
  float gv[4], bbv[4];
  if (DO_LN) {
#pragma unroll
    for (int n = 0; n < 4; ++n) {
      int c = wn * 64 + n * 16 + l15;
      gv[n] = g[c];
      bbv[n] = b[c];
    }
  }
#pragma unroll
  for (int m = 0; m < 4; ++m)
#pragma unroll
    for (int j = 0; j < 4; ++j) {
      int r = wm * 64 + m * 16 + l4 * 4 + j;
      size_t rowoff = (size_t)(bm + r) * DMODEL + wn * 64 + l15;
      float mean = 0.f, rs = 0.f;
      if (DO_LN) {
        f32x4 sv = *(const f32x4*)redS[r];
        f32x4 qv = *(const f32x4*)redQ[r];
        float ssum = sv[0] + sv[1] + sv[2] + sv[3];
        float qsum = qv[0] + qv[1] + qv[2] + qv[3];
        mean = ssum * (1.0f / DMODEL);
        float var = qsum * (1.0f / DMODEL) - mean * mean;
        rs = rsqrtf(var + 1e-5f);
      }
#pragma unroll
      for (int n = 0; n < 4; ++n) {
        float v = acc[m][n][j];
        x[rowoff + n * 16] = v;
        if (DO_LN)
          xb[rowoff + n * 16] = f2bf((v - mean) * rs * gv[n] + bbv[n]);
      }
    }
}

// ------------------------------------------------------------ attention ----
__global__ __launch_bounds__(256) void attn_kernel(
    const u16* __restrict__ qkv, const int* __restrict__ amask,
    u16* __restrict__ ao) {
  int win = blockIdx.x, h = blockIdx.y, b = blockIdx.z;
  int tid = threadIdx.x, lane = tid & 63, wid = tid >> 6;
  int l15 = lane & 15, l4 = lane >> 4;

  __shared__ u16 Ks[192 * 32];
  __shared__ u16 Vts[32 * 200];
  __shared__ u16 Ps[64 * 200];
  __shared__ unsigned char valid[192];

  int t0 = win * WIN - WIN;

  if (tid < 192) {
    int t = t0 + tid;
    valid[tid] = (t >= 0 && t < S_LEN && amask[b * S_LEN + t] != 0) ? 1 : 0;
  }
#pragma unroll
  for (int c = 0; c < 3; ++c) {
    int chunk = c * 256 + tid;
    int key = chunk >> 2, kc = chunk & 3;
    int t = t0 + key;
    t = t < 0 ? 0 : (t >= S_LEN ? S_LEN - 1 : t);
    const u16* gp = qkv + (size_t)(b * S_LEN + t) * 768 + 256 + h * 32 + kc * 8;
    gload_lds16(gp, (char*)Ks + c * 4096 + wid * 1024);
  }
  for (int e = tid; e < 192 * 32; e += 256) {
    int key = e >> 5, d = e & 31;
    int t = t0 + key;
    t = t < 0 ? 0 : (t >= S_LEN ? S_LEN - 1 : t);
    Vts[d * 200 + key] = qkv[(size_t)(b * S_LEN + t) * 768 + 512 + h * 32 + d];
  }
  __syncthreads();

  int qrow = b * S_LEN + win * WIN + wid * 16 + l15;
  f32x4 aq = *(const f32x4*)(qkv + (size_t)qrow * 768 + h * 32 + l4 * 8);

  f32x4 sacc[12] = {};
#pragma unroll
  for (int f = 0; f < 12; ++f) {
    f32x4 bk = *(const f32x4*)(Ks + (f * 16 + l15) * 32 + l4 * 8);
    mfma16(sacc[f], aq, bk);
  }
  MFMA_FENCE();

  const float scale = 0.17677669529663687f;
  float mrow[4] = {-1e30f, -1e30f, -1e30f, -1e30f};
#pragma unroll
  for (int f = 0; f < 12; ++f) {
    bool ok = valid[f * 16 + l15] != 0;
#pragma unroll
    for (int j = 0; j < 4; ++j) {
      float sv = ok ? sacc[f][j] * scale : -1e9f;
      sacc[f][j] = sv;
      mrow[j] = fmaxf(mrow[j], sv);
    }
  }
#pragma unroll
  for (int j = 0; j < 4; ++j)
#pragma unroll
    for (int off = 1; off < 16; off <<= 1)
      mrow[j] = fmaxf(mrow[j], __shfl_xor(mrow[j], off, 64));

  float ssum[4] = {0.f, 0.f, 0.f, 0.f};
#pragma unroll
  for (int f = 0; f < 12; ++f)
#pragma unroll
    for (int j = 0; j < 4; ++j) {
      float p = __expf(sacc[f][j] - mrow[j]);
      sacc[f][j] = p;
      ssum[j] += p;
    }
#pragma unroll
  for (int j = 0; j < 4; ++j)
#pragma unroll
    for (int off = 1; off < 16; off <<= 1)
      ssum[j] += __shfl_xor(ssum[j], off, 64);

#pragma unroll
  for (int f = 0; f < 12; ++f)
#pragma unroll
    for (int j = 0; j < 4; ++j)
      Ps[(wid * 16 + l4 * 4 + j) * 200 + f * 16 + l15] = f2bf(sacc[f][j]);
  __syncthreads();

  f32x4 oacc[2] = {};
#pragma unroll
  for (int kk = 0; kk < 6; ++kk) {
    f32x4 ap = *(const f32x4*)(Ps + (wid * 16 + l15) * 200 + kk * 32 + l4 * 8);
#pragma unroll
    for (int nf = 0; nf < 2; ++nf) {
      f32x4 bv = *(const f32x4*)(Vts + (nf * 16 + l15) * 200 + kk * 32 + l4 * 8);
      mfma16(oacc[nf], ap, bv);
    }
  }
  MFMA_FENCE();

  float inv[4];
#pragma unroll
  for (int j = 0; j < 4; ++j) inv[j] = 1.0f / ssum[j];
#pragma unroll
  for (int nf = 0; nf < 2; ++nf)
#pragma unroll
    for (int j = 0; j < 4; ++j) {
      int orow = b * S_LEN + win * WIN + wid * 16 + l4 * 4 + j;
      ao[(size_t)orow * 256 + h * 32 + nf * 16 + l15] = f2bf(oacc[nf][j] * inv[j]);
    }
}

// ------------------------------------------------------------- scan --------
__global__ __launch_bounds__(256) void scan_kernel(const int* __restrict__ wsrt,
                                                   int* __restrict__ tgt) {
  __shared__ int part[256];
  int b = blockIdx.x, tid = threadIdx.x;
  const int* src = wsrt + b * S_LEN;
  int* dst = tgt + b * S_LEN;
  int base = tid * 32;
  int loc[32];
  int s = 0;
#pragma unroll
  for (int i = 0; i < 32; ++i) {
    loc[i] = src[base + i];
    s += loc[i];
  }
  part[tid] = s;
  __syncthreads();
  for (int off = 1; off < 256; off <<= 1) {
    int v = (tid >= off) ? part[tid - off] : 0;
    __syncthreads();
    part[tid] += v;
    __syncthreads();
  }
  int cum = part[tid] - s;
#pragma unroll
  for (int i = 0; i < 32; ++i) {
    cum += loc[i];
    dst[base + i] = (loc[i] > 0) ? (cum - 1) : -1;
  }
}

// ------------------------------------------------- final LN + gather -------
__global__ __launch_bounds__(64) void gather_ln_kernel(
    const float* __restrict__ x, const int* __restrict__ tgt,
    const float* __restrict__ g, const float* __restrict__ b,
    float* __restrict__ out) {
  int r = blockIdx.x;
  int tg = tgt[r];
  if (tg < 0) return;
  int bIdx = r >> 13;
  int lane = threadIdx.x;
  f32x4 v = *(const f32x4*)(x + (size_t)r * DMODEL + lane * 4);
  float s = v[0] + v[1] + v[2] + v[3];
  float q = v[0] * v[0] + v[1] * v[1] + v[2] * v[2] + v[3] * v[3];
  for (int off = 32; off; off >>= 1) {
    s += __shfl_xor(s, off, 64);
    q += __shfl_xor(q, off, 64);
  }
  float mean = s * (1.0f / DMODEL);
  float var = q * (1.0f / DMODEL) - mean * mean;
  float rs = rsqrtf(var + 1e-5f);
  f32x4 gg = *(const f32x4*)(g + lane * 4);
  f32x4 bb = *(const f32x4*)(b + lane * 4);
  f32x4 o;
  for (int j = 0; j < 4; ++j) o[j] = (v[j] - mean) * rs * gg[j] + bb[j];
  *(f32x4*)(out + (size_t)(bIdx * S_LEN + tg) * DMODEL + lane * 4) = o;
}

// ---------------------------------------------------------------------------
extern "C" void kernel_launch(void* const* d_in, const int* in_sizes, int n_in,
                              void* d_out, int out_size, void* d_ws,
                              size_t ws_size, hipStream_t stream) {
  const int* ids = (const int*)d_in[0];
  const int* amask = (const int*)d_in[1];
  const int* wstart = (const int*)d_in[2];
  const float* emb = (const float*)d_in[3];
  const float* pos = (const float*)d_in[4];
  const float* ln1g = (const float*)d_in[5];
  const float* ln1b = (const float*)d_in[6];
  const float* wq = (const float*)d_in[7];
  const float* wk = (const float*)d_in[8];
  const float* wv = (const float*)d_in[9];
  const float* wo = (const float*)d_in[10];
  const float* ln2g = (const float*)d_in[11];
  const float* ln2b = (const float*)d_in[12];
  const float* w1 = (const float*)d_in[13];
  const float* b1 = (const float*)d_in[14];
  const float* w2 = (const float*)d_in[15];
  const float* b2 = (const float*)d_in[16];
  const float* lnfg = (const float*)d_in[17];
  const float* lnfb = (const float*)d_in[18];

  char* ws = (char*)d_ws;
  const size_t OFF_X = 0;              // f32 [32768][256]
  const size_t OFF_XB = 33554432;      // bf16 [32768][256]
  const size_t OFF_AO = 50331648;      // bf16 [32768][256]
  const size_t OFF_BIG = 67108864;     // bf16 qkv [32768][768] / ffh [32768][1024]
  const size_t OFF_WQKVT = 134217728;  // bf16 [6][768][256]
  const size_t OFF_WOT = 136577024;    // bf16 [6][256][256]
  const size_t OFF_W1T = 137363456;    // bf16 [6][1024][256]
  const size_t OFF_W2T = 140509184;    // bf16 [6][256][1024]
  const size_t OFF_TGT = 143654912;    // int [32768]
  const size_t NEEDED = 143785984;
  if (ws_size < NEEDED) return;

  float* x = (float*)(ws + OFF_X);
  u16* xb = (u16*)(ws + OFF_XB);
  u16* ao = (u16*)(ws + OFF_AO);
  u16* big = (u16*)(ws + OFF_BIG);
  u16* WqkvT = (u16*)(ws + OFF_WQKVT);
  u16* WoT = (u16*)(ws + OFF_WOT);
  u16* W1T = (u16*)(ws + OFF_W1T);
  u16* W2T = (u16*)(ws + OFF_W2T);
  int* tgt = (int*)(ws + OFF_TGT);

  tcast_kernel<<<1024, 256, 0, stream>>>(wq, WqkvT, NLAYER * 256 * 256, 256, 256, 768 * 256, 0);
  tcast_kernel<<<1024, 256, 0, stream>>>(wk, WqkvT, NLAYER * 256 * 256, 256, 256, 768 * 256, 256);
  tcast_kernel<<<1024, 256, 0, stream>>>(wv, WqkvT, NLAYER * 256 * 256, 256, 256, 768 * 256, 512);
  tcast_kernel<<<1024, 256, 0, stream>>>(wo, WoT, NLAYER * 256 * 256, 256, 256, 256 * 256, 0);
  tcast_kernel<<<2048, 256, 0, stream>>>(w1, W1T, NLAYER * 256 * 1024, 256, 1024, 1024 * 256, 0);
  tcast_kernel<<<2048, 256, 0, stream>>>(w2, W2T, NLAYER * 1024 * 256, 1024, 256, 256 * 1024, 0);

  embed_ln_kernel<<<MROWS / 4, 256, 0, stream>>>(ids, emb, pos, ln1g, ln1b, x, xb);
  zero_kernel<<<2048, 256, 0, stream>>>((float*)d_out, out_size / 4);
  scan_kernel<<<BATCH, 256, 0, stream>>>(wstart, tgt);

  for (int l = 0; l < NLAYER; ++l) {
    // qkv = xb @ WqkvT[l]   (N=768, nx=6, 1536 blocks)
    gemm_bf16<false, false><<<1536, 256, 0, stream>>>(
        xb, WqkvT + (size_t)l * 768 * 256, big, nullptr, 768, 256, 6);
    // attention
    attn_kernel<<<dim3(NWIN, NHEAD, BATCH), 256, 0, stream>>>(big, amask, ao);
    // x += ao @ WoT[l]; xb = LN2(x)
    gemm_res_ln<true><<<MROWS / 128, 512, 0, stream>>>(
        ao, WoT + (size_t)l * 256 * 256, x, xb, nullptr,
        ln2g + l * DMODEL, ln2b + l * DMODEL, 256);
    // ffh = gelu(xb @ W1T[l] + b1)   (N=1024, nx=8, 2048 blocks)
    gemm_bf16<true, true><<<2048, 256, 0, stream>>>(
        xb, W1T + (size_t)l * 1024 * 256, big, b1 + l * FFDIM, 1024, 256, 8);
    // x += ffh @ W2T[l] + b2; xb = LN1[l+1](x)  (last layer: no LN)
    if (l < NLAYER - 1) {
      gemm_res_ln<true><<<MROWS / 128, 512, 0, stream>>>(
          big, W2T + (size_t)l * 256 * 1024, x, xb, b2 + l * DMODEL,
          ln1g + (l + 1) * DMODEL, ln1b + (l + 1) * DMODEL, 1024);
    } else {
      gemm_res_ln<false><<<MROWS / 128, 512, 0, stream>>>(
          big, W2T + (size_t)l * 256 * 1024, x, nullptr, b2 + l * DMODEL,
          nullptr, nullptr, 1024);
    }
  }

  gather_ln_kernel<<<MROWS, 64, 0, stream>>>(x, tgt, lnfg, lnfb, (float*)d_out);
}